// Round 5
// baseline (364.402 us; speedup 1.0000x reference)
//
#include <hip/hip_runtime.h>
#include <hip/hip_fp16.h>
#include <math.h>

#define NN 50000
#define NE 800000
#define DD 128
#define NG 64
#define NEG 0.2f
#define NBLK 49          // scan blocks: ceil(50000/1024)

__device__ __forceinline__ float leaky(float x) { return x >= 0.f ? x : NEG * x; }

__device__ __forceinline__ float wave_sum(float v) {
    #pragma unroll
    for (int o = 32; o; o >>= 1) v += __shfl_xor(v, o, 64);
    return v;
}

// ---------------- CSR build ----------------
// 4 edges per thread via int4 loads
__global__ void k_hist(const int* __restrict__ dst, int* __restrict__ deg) {
    int e = blockIdx.x * 256 + threadIdx.x;          // e indexes groups of 4
    if (e < NE / 4) {
        int4 d = ((const int4*)dst)[e];
        atomicAdd(&deg[d.x], 1);
        atomicAdd(&deg[d.y], 1);
        atomicAdd(&deg[d.z], 1);
        atomicAdd(&deg[d.w], 1);
    }
}

// per-block exclusive scan + block sums
__global__ void k_scan1(const int* __restrict__ deg, int* __restrict__ row,
                        int* __restrict__ bsum) {
    __shared__ int wsum[16];
    int tid = threadIdx.x, lane = tid & 63, w = tid >> 6;
    int i = blockIdx.x * 1024 + tid;
    int v = (i < NN) ? deg[i] : 0;
    int x = v;
    #pragma unroll
    for (int s = 1; s < 64; s <<= 1) {
        int t = __shfl_up(x, s, 64);
        if (lane >= s) x += t;
    }
    if (lane == 63) wsum[w] = x;
    __syncthreads();
    if (tid < 16) {
        int t = wsum[tid];
        #pragma unroll
        for (int s = 1; s < 16; s <<= 1) {
            int u = __shfl_up(t, s, 64);
            if (tid >= s) t += u;
        }
        wsum[tid] = t;
    }
    __syncthreads();
    int woff = w ? wsum[w - 1] : 0;
    if (i < NN) row[i] = woff + x - v;            // block-local exclusive
    if (tid == 1023) bsum[blockIdx.x] = wsum[15]; // block total
}

// add block offsets (block offset computed in-kernel; also writes row[NN])
__global__ void k_scan3(const int* __restrict__ bsum, int* __restrict__ row) {
    __shared__ int boff_s;
    __shared__ int tot_s;
    int tid = threadIdx.x;
    if (tid < 64) {
        int t = (tid < NBLK) ? bsum[tid] : 0;
        int x = t;
        #pragma unroll
        for (int s = 1; s < 64; s <<= 1) {
            int u = __shfl_up(x, s, 64);
            if (tid >= s) x += u;
        }
        if (tid == (int)blockIdx.x) boff_s = x - t;     // exclusive prefix
        if (tid == NBLK - 1) tot_s = x;                 // grand total
    }
    __syncthreads();
    int i = blockIdx.x * 1024 + tid;
    if (i < NN) row[i] += boff_s;
    if (i == 0) row[NN] = tot_s;
}

// 4 edges per thread via int4 loads
__global__ void k_scatter(const int* __restrict__ src, const int* __restrict__ dst,
                          const int* __restrict__ row, int* __restrict__ cursor,
                          int* __restrict__ csr) {
    int e = blockIdx.x * 256 + threadIdx.x;
    if (e < NE / 4) {
        int4 s = ((const int4*)src)[e];
        int4 d = ((const int4*)dst)[e];
        csr[row[d.x] + atomicAdd(&cursor[d.x], 1)] = s.x;
        csr[row[d.y] + atomicAdd(&cursor[d.y], 1)] = s.y;
        csr[row[d.z] + atomicAdd(&cursor[d.z], 1)] = s.z;
        csr[row[d.w] + atomicAdd(&cursor[d.w], 1)] = s.w;
    }
}

// ---------------- Hh = fp16(X @ W), asrc/adst fp32 ----------------
// 4 waves/block, 32 rows/block (8/wave). X tile in LDS (16 KB -> 8 blocks/CU),
// grid 1564 (~6 blocks/CU) for occupancy. W streamed from global (L2-resident)
// with one-iteration (8-k) register prefetch depth. H stored fp16 only.
__launch_bounds__(256)
__global__ void k_gemm(const float* __restrict__ X, const float* __restrict__ W,
                       const float* __restrict__ att_s, const float* __restrict__ att_d,
                       __half* __restrict__ Hh, float* __restrict__ asrc,
                       float* __restrict__ adst) {
    __shared__ __align__(16) float Xs[32 * DD];    // 16 KB
    int tid = threadIdx.x;
    int rowbase = blockIdx.x * 32;
    {
        const float4* X4 = (const float4*)X;
        float4* Xs4 = (float4*)Xs;
        size_t base4 = (size_t)rowbase * (DD / 4);
        const size_t max4 = (size_t)NN * (DD / 4) - 1;
        #pragma unroll
        for (int i = 0; i < 4; i++) {              // 32*128/4/256
            size_t g = base4 + tid + i * 256;
            if (g > max4) g = max4;                // tail clamp (loads only)
            Xs4[tid + i * 256] = X4[g];
        }
    }
    __syncthreads();
    int lane = tid & 63;
    int w = tid >> 6;
    int wrow = w * 8;
    float2 acc[8];
    #pragma unroll
    for (int r = 0; r < 8; r++) acc[r] = make_float2(0.f, 0.f);

    const float2* W2 = (const float2*)W;           // W[k][2l..2l+1] = W2[k*64+l]
    float2 wa[4], wb[4];
    #pragma unroll
    for (int u = 0; u < 4; u++) wa[u] = W2[u * 64 + lane];
    #pragma unroll
    for (int u = 0; u < 4; u++) wb[u] = W2[(4 + u) * 64 + lane];

    #pragma unroll 1
    for (int k0 = 0; k0 < DD; k0 += 8) {
        float2 na[4], nb[4];
        int kp = (k0 + 8) & 127;                   // wrap: last iter loads k=0 (unused)
        #pragma unroll
        for (int u = 0; u < 4; u++) na[u] = W2[(kp + u) * 64 + lane];
        #pragma unroll
        for (int u = 0; u < 4; u++) nb[u] = W2[(kp + 4 + u) * 64 + lane];
        #pragma unroll
        for (int r = 0; r < 8; r++) {
            float4 xv = *(const float4*)&Xs[(wrow + r) * DD + k0];      // broadcast
            float4 xw = *(const float4*)&Xs[(wrow + r) * DD + k0 + 4];
            acc[r].x = fmaf(xv.x, wa[0].x, acc[r].x);
            acc[r].y = fmaf(xv.x, wa[0].y, acc[r].y);
            acc[r].x = fmaf(xv.y, wa[1].x, acc[r].x);
            acc[r].y = fmaf(xv.y, wa[1].y, acc[r].y);
            acc[r].x = fmaf(xv.z, wa[2].x, acc[r].x);
            acc[r].y = fmaf(xv.z, wa[2].y, acc[r].y);
            acc[r].x = fmaf(xv.w, wa[3].x, acc[r].x);
            acc[r].y = fmaf(xv.w, wa[3].y, acc[r].y);
            acc[r].x = fmaf(xw.x, wb[0].x, acc[r].x);
            acc[r].y = fmaf(xw.x, wb[0].y, acc[r].y);
            acc[r].x = fmaf(xw.y, wb[1].x, acc[r].x);
            acc[r].y = fmaf(xw.y, wb[1].y, acc[r].y);
            acc[r].x = fmaf(xw.z, wb[2].x, acc[r].x);
            acc[r].y = fmaf(xw.z, wb[2].y, acc[r].y);
            acc[r].x = fmaf(xw.w, wb[3].x, acc[r].x);
            acc[r].y = fmaf(xw.w, wb[3].y, acc[r].y);
        }
        #pragma unroll
        for (int u = 0; u < 4; u++) { wa[u] = na[u]; wb[u] = nb[u]; }
    }
    float2 as = ((const float2*)att_s)[lane];
    float2 ad = ((const float2*)att_d)[lane];
    #pragma unroll
    for (int r = 0; r < 8; r++) {
        int rr = rowbase + wrow + r;
        float ps = acc[r].x * as.x + acc[r].y * as.y;
        float pd = acc[r].x * ad.x + acc[r].y * ad.y;
        #pragma unroll
        for (int o = 32; o; o >>= 1) {
            ps += __shfl_xor(ps, o, 64);
            pd += __shfl_xor(pd, o, 64);
        }
        if (rr < NN) {
            ((__half2*)Hh)[(size_t)rr * 64 + lane] = __floats2half2_rn(acc[r].x, acc[r].y);
            if (lane == 0) { asrc[rr] = ps; adst[rr] = pd; }
        }
    }
}

// ---------------- per-dst softmax + weighted aggregation ----------------
// One wave per dst node. Adjacency + self-loop (deg+1 <= 64) cached in regs via
// one coalesced load; per-edge exp cached in regs; pass 2 gets (src, coef) via
// __shfl only. Quarter-wave gather: 16 lanes/row (uint4 = 8 fp16 = 16 B/lane),
// 4 rows per load instr, 16 edges (4 loads, 4 KB) in flight per iteration.
__launch_bounds__(256)
__global__ void k_aggr(const __half* __restrict__ Hh, const float* __restrict__ asrc,
                       const float* __restrict__ adst, const int* __restrict__ row,
                       const int* __restrict__ csr, const float* __restrict__ bias,
                       float* __restrict__ Y) {
    int tid = threadIdx.x;
    int lane = tid & 63;
    int h = lane >> 4;                 // quarter id: edge slot within group of 4
    int fl = lane & 15;                // feature lane (8 fp16 each)
    int w = tid >> 6;
    int v = blockIdx.x * 4 + w;
    if (v >= NN) return;
    float adv = adst[v];
    float e_self = __expf(leaky(asrc[v] + adv));
    int start = row[v], end = row[v + 1];
    int deg = end - start;
    bool self_in_reg = (deg < 64);
    int lim = self_in_reg ? deg + 1 : 64;   // reg-cached slots (incl. self)

    // pass 1: cache adjacency + exp in registers; lane==deg holds the self loop
    int   sarr = v;
    float evl  = 0.f;
    if (lane < lim) {
        sarr = (lane < deg) ? csr[start + lane] : v;
        evl  = (lane < deg) ? __expf(leaky(asrc[sarr] + adv)) : e_self;
    }
    float sloc = evl;
    for (int j = 64 + lane; j < deg; j += 64)      // overflow (deg>=64: unused here)
        sloc += __expf(leaky(asrc[csr[start + j]] + adv));
    float ssum = wave_sum(sloc) + (self_in_reg ? 0.f : e_self);
    float inv = 1.f / (ssum + 1e-16f);

    const uint4* H4 = (const uint4*)Hh;            // row = 16 uint4 (256 B)
    float acc[8];
    #pragma unroll
    for (int t = 0; t < 8; t++) acc[t] = 0.f;

    for (int j = 0; j < lim; j += 16) {            // 16 edges per batch
        int su[4]; float cu[4];
        #pragma unroll
        for (int u = 0; u < 4; u++) {
            int idx = j + 4 * u + h;
            int im  = idx & 63;
            int   s = __shfl(sarr, im, 64);
            float p = __shfl(evl,  im, 64);
            bool ok = idx < lim;
            su[u] = ok ? s : v;
            cu[u] = ok ? p * inv : 0.f;
        }
        uint4 hv[4];
        #pragma unroll
        for (int u = 0; u < 4; u++)
            hv[u] = H4[(size_t)su[u] * 16 + fl];   // 4 independent 1KB wave-loads
        #pragma unroll
        for (int u = 0; u < 4; u++) {
            const __half2* p2 = (const __half2*)&hv[u];
            #pragma unroll
            for (int t = 0; t < 4; t++) {
                float2 f = __half22float2(p2[t]);
                acc[2 * t]     = fmaf(cu[u], f.x, acc[2 * t]);
                acc[2 * t + 1] = fmaf(cu[u], f.y, acc[2 * t + 1]);
            }
        }
    }
    // overflow tail (deg>=64: unused for this graph) + deferred self loop
    if (!self_in_reg) {
        for (int j = 64; j <= deg; ++j) {          // j==deg -> self
            int s = (j < deg) ? csr[start + j] : v;
            float c = (h == 0) ? ((j < deg) ? __expf(leaky(asrc[s] + adv)) : e_self) * inv : 0.f;
            uint4 hv = H4[(size_t)s * 16 + fl];
            const __half2* p2 = (const __half2*)&hv;
            #pragma unroll
            for (int t = 0; t < 4; t++) {
                float2 f = __half22float2(p2[t]);
                acc[2 * t]     = fmaf(c, f.x, acc[2 * t]);
                acc[2 * t + 1] = fmaf(c, f.y, acc[2 * t + 1]);
            }
        }
    }
    // combine the 4 quarters
    #pragma unroll
    for (int t = 0; t < 8; t++) {
        acc[t] += __shfl_xor(acc[t], 16, 64);
        acc[t] += __shfl_xor(acc[t], 32, 64);
    }
    if (lane < 16) {                               // fl == lane
        const float4* B4 = (const float4*)bias;
        float4 b0 = B4[2 * fl], b1 = B4[2 * fl + 1];
        float4 o0, o1;
        o0.x = fmaxf(acc[0] + b0.x, 0.f);
        o0.y = fmaxf(acc[1] + b0.y, 0.f);
        o0.z = fmaxf(acc[2] + b0.z, 0.f);
        o0.w = fmaxf(acc[3] + b0.w, 0.f);
        o1.x = fmaxf(acc[4] + b1.x, 0.f);
        o1.y = fmaxf(acc[5] + b1.y, 0.f);
        o1.z = fmaxf(acc[6] + b1.z, 0.f);
        o1.w = fmaxf(acc[7] + b1.w, 0.f);
        float4* Yo = (float4*)(Y + (size_t)v * DD);
        Yo[2 * fl]     = o0;
        Yo[2 * fl + 1] = o1;
    }
}

// ---------------- global mean pool (batch sorted) ----------------
__launch_bounds__(256)
__global__ void k_pool(const float* __restrict__ Y, const int* __restrict__ batch,
                       float* __restrict__ gsum, int* __restrict__ gcnt) {
    int lane = threadIdx.x & 63;
    int w = __builtin_amdgcn_readfirstlane((int)(threadIdx.x >> 6));
    int wid = blockIdx.x * 4 + w;                  // 0..1023
    const int NPW = (NN + 1023) / 1024;            // 49
    int n0 = wid * NPW, n1 = n0 + NPW;
    if (n1 > NN) n1 = NN;
    const float2* Y2 = (const float2*)Y;
    float2 acc = make_float2(0.f, 0.f);
    int cur = -1, cnt = 0;
    for (int n = n0; n < n1; ++n) {
        int b = batch[n];
        if (b != cur) {
            if (cnt) {
                atomicAdd(&gsum[cur * DD + 2 * lane], acc.x);
                atomicAdd(&gsum[cur * DD + 2 * lane + 1], acc.y);
                if (lane == 0) atomicAdd(&gcnt[cur], cnt);
            }
            acc = make_float2(0.f, 0.f); cnt = 0; cur = b;
        }
        float2 yv = Y2[(size_t)n * 64 + lane];
        acc.x += yv.x; acc.y += yv.y; cnt++;
    }
    if (cnt) {
        atomicAdd(&gsum[cur * DD + 2 * lane], acc.x);
        atomicAdd(&gsum[cur * DD + 2 * lane + 1], acc.y);
        if (lane == 0) atomicAdd(&gcnt[cur], cnt);
    }
}

// ---------------- final MLP: relu(g@W1+b1)@W2+b2 ----------------
__launch_bounds__(128)
__global__ void k_mlp(const float* __restrict__ gsum, const int* __restrict__ gcnt,
                      const float* __restrict__ W1, const float* __restrict__ b1,
                      const float* __restrict__ W2, const float* __restrict__ b2,
                      float* __restrict__ out) {
    __shared__ float g[DD];
    __shared__ float red[2];
    int gi = blockIdx.x, t = threadIdx.x;
    float cnt = fmaxf((float)gcnt[gi], 1.f);
    g[t] = gsum[gi * DD + t] / cnt;
    __syncthreads();
    float a = b1[t];
    #pragma unroll 4
    for (int k = 0; k < DD; k++) a = fmaf(g[k], W1[k * DD + t], a);
    float h = fmaxf(a, 0.f);
    float p = h * W2[t];
    p = wave_sum(p);
    int lane = t & 63, w = t >> 6;
    if (lane == 0) red[w] = p;
    __syncthreads();
    if (t == 0) out[gi] = red[0] + red[1] + b2[0];
}

extern "C" void kernel_launch(void* const* d_in, const int* in_sizes, int n_in,
                              void* d_out, int out_size, void* d_ws, size_t ws_size,
                              hipStream_t stream) {
    const float* x    = (const float*)d_in[0];
    const int*   ei   = (const int*)d_in[1];
    const int*   bat  = (const int*)d_in[3];
    const float* Wg1  = (const float*)d_in[4];
    const float* as1  = (const float*)d_in[5];
    const float* ad1  = (const float*)d_in[6];
    const float* bg1  = (const float*)d_in[7];
    const float* Wg2  = (const float*)d_in[8];
    const float* as2  = (const float*)d_in[9];
    const float* ad2  = (const float*)d_in[10];
    const float* bg2  = (const float*)d_in[11];
    const float* Wl1  = (const float*)d_in[12];
    const float* bl1  = (const float*)d_in[13];
    const float* Wl2  = (const float*)d_in[14];
    const float* bl2  = (const float*)d_in[15];
    const int* src = ei;
    const int* dst = ei + NE;

    char* ws = (char*)d_ws;
    const size_t SZ_FEAT = (size_t)NN * DD * 4;     // 25,600,000
    __half* Hh  = (__half*)(ws);                    // 12.8 MB (within old H slot)
    float* Y    = (float*)(ws + SZ_FEAT);
    float* asrc = (float*)(ws + 2 * SZ_FEAT);
    float* adst = (float*)(ws + 2 * SZ_FEAT + 200000);
    int*   deg  = (int*)  (ws + 2 * SZ_FEAT + 400000);   // zero region start
    int*   cur  = (int*)  (ws + 2 * SZ_FEAT + 600000);
    float* gsum = (float*)(ws + 2 * SZ_FEAT + 800000);
    int*   gcnt = (int*)  (ws + 2 * SZ_FEAT + 800000 + NG * DD * 4);
    int*   row  = (int*)  (ws + 2 * SZ_FEAT + 800000 + NG * DD * 4 + 256);
    int*   csr  = (int*)  (ws + 2 * SZ_FEAT + 800000 + NG * DD * 4 + 256 + 200064);
    int*   bsum = (int*)  (ws + 2 * SZ_FEAT + 800000 + NG * DD * 4 + 256 + 200064 + (size_t)NE * 4);

    // zero: deg (200000) + cur (200000) + gsum (32768) + gcnt (256)
    hipMemsetAsync(deg, 0, 200000 + 200000 + NG * DD * 4 + 256, stream);

    k_hist   <<<(NE / 4 + 255) / 256, 256, 0, stream>>>(dst, deg);
    k_scan1  <<<NBLK, 1024, 0, stream>>>(deg, row, bsum);
    k_scan3  <<<NBLK, 1024, 0, stream>>>(bsum, row);
    k_scatter<<<(NE / 4 + 255) / 256, 256, 0, stream>>>(src, dst, row, cur, csr);

    int gemm_blocks = (NN + 31) / 32;               // 32 rows / block
    k_gemm<<<gemm_blocks, 256, 0, stream>>>(x, Wg1, as1, ad1, Hh, asrc, adst);
    k_aggr<<<(NN + 3) / 4, 256, 0, stream>>>(Hh, asrc, adst, row, csr, bg1, Y);
    k_gemm<<<gemm_blocks, 256, 0, stream>>>(Y, Wg2, as2, ad2, Hh, asrc, adst);
    k_aggr<<<(NN + 3) / 4, 256, 0, stream>>>(Hh, asrc, adst, row, csr, bg2, Y);

    k_pool<<<256, 256, 0, stream>>>(Y, bat, gsum, gcnt);
    k_mlp <<<NG, 128, 0, stream>>>(gsum, gcnt, Wl1, bl1, Wl2, bl2, (float*)d_out);
}

// Round 6
// 325.982 us; speedup vs baseline: 1.1179x; 1.1179x over previous
//
#include <hip/hip_runtime.h>
#include <hip/hip_fp16.h>
#include <math.h>

#define NN 50000
#define NE 800000
#define DD 128
#define NG 64
#define NEG 0.2f
#define KMAX 64                  // fixed-width adjacency slots per node
#define OCAP 65536               // overflow pair capacity (never hit: deg<=~40)
#define GEMM_BLOCKS ((NN + 31) / 32)          // 1563
#define BUILD_BLOCKS ((NE / 4 + 255) / 256)   // 782

__device__ __forceinline__ float leaky(float x) { return x >= 0.f ? x : NEG * x; }

__device__ __forceinline__ float wave_sum(float v) {
    #pragma unroll
    for (int o = 32; o; o >>= 1) v += __shfl_xor(v, o, 64);
    return v;
}

// ---------------- gemm body (shared by fused + standalone) ----------------
// 4 waves/block, 32 rows/block (8/wave). X tile in LDS (16 KB), W streamed
// from global (L2-resident) with one-iteration (8-k) register prefetch.
// Output H stored fp16 only; asrc/adst fp32.
__device__ __forceinline__ void gemm_body(
        int gblk, const float* __restrict__ X, const float* __restrict__ W,
        const float* __restrict__ att_s, const float* __restrict__ att_d,
        __half* __restrict__ Hh, float* __restrict__ asrc, float* __restrict__ adst) {
    __shared__ __align__(16) float Xs[32 * DD];    // 16 KB
    int tid = threadIdx.x;
    int rowbase = gblk * 32;
    {
        const float4* X4 = (const float4*)X;
        float4* Xs4 = (float4*)Xs;
        size_t base4 = (size_t)rowbase * (DD / 4);
        const size_t max4 = (size_t)NN * (DD / 4) - 1;
        #pragma unroll
        for (int i = 0; i < 4; i++) {              // 32*128/4/256
            size_t g = base4 + tid + i * 256;
            if (g > max4) g = max4;                // tail clamp (loads only)
            Xs4[tid + i * 256] = X4[g];
        }
    }
    __syncthreads();
    int lane = tid & 63;
    int w = tid >> 6;
    int wrow = w * 8;
    float2 acc[8];
    #pragma unroll
    for (int r = 0; r < 8; r++) acc[r] = make_float2(0.f, 0.f);

    const float2* W2 = (const float2*)W;           // W[k][2l..2l+1] = W2[k*64+l]
    float2 wa[4], wb[4];
    #pragma unroll
    for (int u = 0; u < 4; u++) wa[u] = W2[u * 64 + lane];
    #pragma unroll
    for (int u = 0; u < 4; u++) wb[u] = W2[(4 + u) * 64 + lane];

    #pragma unroll 1
    for (int k0 = 0; k0 < DD; k0 += 8) {
        float2 na[4], nb[4];
        int kp = (k0 + 8) & 127;                   // wrap: last iter loads k=0 (unused)
        #pragma unroll
        for (int u = 0; u < 4; u++) na[u] = W2[(kp + u) * 64 + lane];
        #pragma unroll
        for (int u = 0; u < 4; u++) nb[u] = W2[(kp + 4 + u) * 64 + lane];
        #pragma unroll
        for (int r = 0; r < 8; r++) {
            float4 xv = *(const float4*)&Xs[(wrow + r) * DD + k0];      // broadcast
            float4 xw = *(const float4*)&Xs[(wrow + r) * DD + k0 + 4];
            acc[r].x = fmaf(xv.x, wa[0].x, acc[r].x);
            acc[r].y = fmaf(xv.x, wa[0].y, acc[r].y);
            acc[r].x = fmaf(xv.y, wa[1].x, acc[r].x);
            acc[r].y = fmaf(xv.y, wa[1].y, acc[r].y);
            acc[r].x = fmaf(xv.z, wa[2].x, acc[r].x);
            acc[r].y = fmaf(xv.z, wa[2].y, acc[r].y);
            acc[r].x = fmaf(xv.w, wa[3].x, acc[r].x);
            acc[r].y = fmaf(xv.w, wa[3].y, acc[r].y);
            acc[r].x = fmaf(xw.x, wb[0].x, acc[r].x);
            acc[r].y = fmaf(xw.x, wb[0].y, acc[r].y);
            acc[r].x = fmaf(xw.y, wb[1].x, acc[r].x);
            acc[r].y = fmaf(xw.y, wb[1].y, acc[r].y);
            acc[r].x = fmaf(xw.z, wb[2].x, acc[r].x);
            acc[r].y = fmaf(xw.z, wb[2].y, acc[r].y);
            acc[r].x = fmaf(xw.w, wb[3].x, acc[r].x);
            acc[r].y = fmaf(xw.w, wb[3].y, acc[r].y);
        }
        #pragma unroll
        for (int u = 0; u < 4; u++) { wa[u] = na[u]; wb[u] = nb[u]; }
    }
    float2 as = ((const float2*)att_s)[lane];
    float2 ad = ((const float2*)att_d)[lane];
    #pragma unroll
    for (int r = 0; r < 8; r++) {
        int rr = rowbase + wrow + r;
        float ps = acc[r].x * as.x + acc[r].y * as.y;
        float pd = acc[r].x * ad.x + acc[r].y * ad.y;
        #pragma unroll
        for (int o = 32; o; o >>= 1) {
            ps += __shfl_xor(ps, o, 64);
            pd += __shfl_xor(pd, o, 64);
        }
        if (rr < NN) {
            ((__half2*)Hh)[(size_t)rr * 64 + lane] = __floats2half2_rn(acc[r].x, acc[r].y);
            if (lane == 0) { asrc[rr] = ps; adst[rr] = pd; }
        }
    }
}

// adjacency build body: rank from atomicAdd return; direct fixed-width store.
__device__ __forceinline__ void build_body(
        int bblk, const int* __restrict__ src, const int* __restrict__ dst,
        int* __restrict__ deg, int* __restrict__ adj,
        int2* __restrict__ opairs, int* __restrict__ ocnt) {
    int e = bblk * 256 + threadIdx.x;              // group of 4 edges
    if (e < NE / 4) {
        int4 s = ((const int4*)src)[e];
        int4 d = ((const int4*)dst)[e];
        int r0 = atomicAdd(&deg[d.x], 1);
        int r1 = atomicAdd(&deg[d.y], 1);
        int r2 = atomicAdd(&deg[d.z], 1);
        int r3 = atomicAdd(&deg[d.w], 1);
        if (r0 < KMAX) adj[(d.x << 6) + r0] = s.x;
        else { int o = atomicAdd(ocnt, 1); if (o < OCAP) opairs[o] = make_int2(s.x, d.x); }
        if (r1 < KMAX) adj[(d.y << 6) + r1] = s.y;
        else { int o = atomicAdd(ocnt, 1); if (o < OCAP) opairs[o] = make_int2(s.y, d.y); }
        if (r2 < KMAX) adj[(d.z << 6) + r2] = s.z;
        else { int o = atomicAdd(ocnt, 1); if (o < OCAP) opairs[o] = make_int2(s.z, d.z); }
        if (r3 < KMAX) adj[(d.w << 6) + r3] = s.w;
        else { int o = atomicAdd(ocnt, 1); if (o < OCAP) opairs[o] = make_int2(s.w, d.w); }
    }
}

// fused: gemm layer-1 (blocks [0,GEMM_BLOCKS)) || adjacency build (rest)
__launch_bounds__(256)
__global__ void k_gemm1_build(const float* __restrict__ X, const float* __restrict__ W,
                              const float* __restrict__ att_s, const float* __restrict__ att_d,
                              __half* __restrict__ Hh, float* __restrict__ asrc,
                              float* __restrict__ adst,
                              const int* __restrict__ src, const int* __restrict__ dst,
                              int* __restrict__ deg, int* __restrict__ adj,
                              int2* __restrict__ opairs, int* __restrict__ ocnt) {
    if (blockIdx.x < GEMM_BLOCKS)
        gemm_body(blockIdx.x, X, W, att_s, att_d, Hh, asrc, adst);
    else
        build_body(blockIdx.x - GEMM_BLOCKS, src, dst, deg, adj, opairs, ocnt);
}

__launch_bounds__(256)
__global__ void k_gemm(const float* __restrict__ X, const float* __restrict__ W,
                       const float* __restrict__ att_s, const float* __restrict__ att_d,
                       __half* __restrict__ Hh, float* __restrict__ asrc,
                       float* __restrict__ adst) {
    gemm_body(blockIdx.x, X, W, att_s, att_d, Hh, asrc, adst);
}

// ---------------- per-dst softmax + weighted aggregation ----------------
// One wave per dst node. Adjacency (fixed-width adj) + self-loop cached in
// regs via one coalesced load; per-edge exp cached in regs; pass 2 gets
// (src, coef) via __shfl only. Quarter-wave gather: 16 lanes/row (uint4 =
// 8 fp16), 4 rows per load instr, 16 edges (4 KB) in flight per iteration.
// No max-subtraction: |alpha| small for this data, fp32 exp cannot overflow.
__launch_bounds__(256)
__global__ void k_aggr(const __half* __restrict__ Hh, const float* __restrict__ asrc,
                       const float* __restrict__ adst, const int* __restrict__ degp,
                       const int* __restrict__ adj, const int2* __restrict__ opairs,
                       const int* __restrict__ ocnt, const float* __restrict__ bias,
                       float* __restrict__ Y) {
    int tid = threadIdx.x;
    int lane = tid & 63;
    int h = lane >> 4;                 // quarter id: edge slot within group of 4
    int fl = lane & 15;                // feature lane (8 fp16 each)
    int w = tid >> 6;
    int v = blockIdx.x * 4 + w;
    if (v >= NN) return;
    float adv = adst[v];
    float e_self = __expf(leaky(asrc[v] + adv));
    int deg = degp[v];
    bool self_in_reg = (deg < KMAX);
    int lim = self_in_reg ? deg + 1 : KMAX;   // reg-cached slots (incl. self)

    // pass 1: cache adjacency + exp in registers; lane==deg holds the self loop
    int   sarr = v;
    float evl  = 0.f;
    if (lane < lim) {
        sarr = (lane < deg) ? adj[(v << 6) + lane] : v;
        evl  = (lane < deg) ? __expf(leaky(asrc[sarr] + adv)) : e_self;
    }
    int oc = 0;
    float sloc = evl;
    if (deg > KMAX) {                              // overflow (never in practice)
        oc = ocnt[0];
        if (oc > OCAP) oc = OCAP;
        for (int j = lane; j < oc; j += 64) {
            int2 p = opairs[j];
            if (p.y == v) sloc += __expf(leaky(asrc[p.x] + adv));
        }
    }
    float ssum = wave_sum(sloc) + (self_in_reg ? 0.f : e_self);
    float inv = 1.f / (ssum + 1e-16f);

    const uint4* H4 = (const uint4*)Hh;            // row = 16 uint4 (256 B)
    float acc[8];
    #pragma unroll
    for (int t = 0; t < 8; t++) acc[t] = 0.f;

    for (int j = 0; j < lim; j += 16) {            // 16 edges per batch
        int su[4]; float cu[4];
        #pragma unroll
        for (int u = 0; u < 4; u++) {
            int idx = j + 4 * u + h;
            int im  = idx & 63;
            int   s = __shfl(sarr, im, 64);
            float p = __shfl(evl,  im, 64);
            bool ok = idx < lim;
            su[u] = ok ? s : v;
            cu[u] = ok ? p * inv : 0.f;
        }
        uint4 hv[4];
        #pragma unroll
        for (int u = 0; u < 4; u++)
            hv[u] = H4[(size_t)su[u] * 16 + fl];   // 4 independent 1KB wave-loads
        #pragma unroll
        for (int u = 0; u < 4; u++) {
            const __half2* p2 = (const __half2*)&hv[u];
            #pragma unroll
            for (int t = 0; t < 4; t++) {
                float2 f = __half22float2(p2[t]);
                acc[2 * t]     = fmaf(cu[u], f.x, acc[2 * t]);
                acc[2 * t + 1] = fmaf(cu[u], f.y, acc[2 * t + 1]);
            }
        }
    }
    if (!self_in_reg) {                            // deferred self + overflow
        {
            float c0 = (h == 0) ? e_self * inv : 0.f;
            uint4 hv = H4[(size_t)v * 16 + fl];
            const __half2* p2 = (const __half2*)&hv;
            #pragma unroll
            for (int t = 0; t < 4; t++) {
                float2 f = __half22float2(p2[t]);
                acc[2 * t]     = fmaf(c0, f.x, acc[2 * t]);
                acc[2 * t + 1] = fmaf(c0, f.y, acc[2 * t + 1]);
            }
        }
        for (int j = 0; j < oc; ++j) {             // expected 0 iterations
            int2 p = opairs[j];
            if (p.y != v) continue;
            float c = (h == 0) ? __expf(leaky(asrc[p.x] + adv)) * inv : 0.f;
            uint4 hv = H4[(size_t)p.x * 16 + fl];
            const __half2* p2 = (const __half2*)&hv;
            #pragma unroll
            for (int t = 0; t < 4; t++) {
                float2 f = __half22float2(p2[t]);
                acc[2 * t]     = fmaf(c, f.x, acc[2 * t]);
                acc[2 * t + 1] = fmaf(c, f.y, acc[2 * t + 1]);
            }
        }
    }
    // combine the 4 quarters
    #pragma unroll
    for (int t = 0; t < 8; t++) {
        acc[t] += __shfl_xor(acc[t], 16, 64);
        acc[t] += __shfl_xor(acc[t], 32, 64);
    }
    if (lane < 16) {                               // fl == lane
        const float4* B4 = (const float4*)bias;
        float4 b0 = B4[2 * fl], b1 = B4[2 * fl + 1];
        float4 o0, o1;
        o0.x = fmaxf(acc[0] + b0.x, 0.f);
        o0.y = fmaxf(acc[1] + b0.y, 0.f);
        o0.z = fmaxf(acc[2] + b0.z, 0.f);
        o0.w = fmaxf(acc[3] + b0.w, 0.f);
        o1.x = fmaxf(acc[4] + b1.x, 0.f);
        o1.y = fmaxf(acc[5] + b1.y, 0.f);
        o1.z = fmaxf(acc[6] + b1.z, 0.f);
        o1.w = fmaxf(acc[7] + b1.w, 0.f);
        float4* Yo = (float4*)(Y + (size_t)v * DD);
        Yo[2 * fl]     = o0;
        Yo[2 * fl + 1] = o1;
    }
}

// ---------------- global mean pool (batch sorted) ----------------
__launch_bounds__(256)
__global__ void k_pool(const float* __restrict__ Y, const int* __restrict__ batch,
                       float* __restrict__ gsum, int* __restrict__ gcnt) {
    int lane = threadIdx.x & 63;
    int w = __builtin_amdgcn_readfirstlane((int)(threadIdx.x >> 6));
    int wid = blockIdx.x * 4 + w;                  // 0..1023
    const int NPW = (NN + 1023) / 1024;            // 49
    int n0 = wid * NPW, n1 = n0 + NPW;
    if (n1 > NN) n1 = NN;
    const float2* Y2 = (const float2*)Y;
    float2 acc = make_float2(0.f, 0.f);
    int cur = -1, cnt = 0;
    for (int n = n0; n < n1; ++n) {
        int b = batch[n];
        if (b != cur) {
            if (cnt) {
                atomicAdd(&gsum[cur * DD + 2 * lane], acc.x);
                atomicAdd(&gsum[cur * DD + 2 * lane + 1], acc.y);
                if (lane == 0) atomicAdd(&gcnt[cur], cnt);
            }
            acc = make_float2(0.f, 0.f); cnt = 0; cur = b;
        }
        float2 yv = Y2[(size_t)n * 64 + lane];
        acc.x += yv.x; acc.y += yv.y; cnt++;
    }
    if (cnt) {
        atomicAdd(&gsum[cur * DD + 2 * lane], acc.x);
        atomicAdd(&gsum[cur * DD + 2 * lane + 1], acc.y);
        if (lane == 0) atomicAdd(&gcnt[cur], cnt);
    }
}

// ---------------- final MLP: relu(g@W1+b1)@W2+b2 ----------------
__launch_bounds__(128)
__global__ void k_mlp(const float* __restrict__ gsum, const int* __restrict__ gcnt,
                      const float* __restrict__ W1, const float* __restrict__ b1,
                      const float* __restrict__ W2, const float* __restrict__ b2,
                      float* __restrict__ out) {
    __shared__ float g[DD];
    __shared__ float red[2];
    int gi = blockIdx.x, t = threadIdx.x;
    float cnt = fmaxf((float)gcnt[gi], 1.f);
    g[t] = gsum[gi * DD + t] / cnt;
    __syncthreads();
    float a = b1[t];
    #pragma unroll 4
    for (int k = 0; k < DD; k++) a = fmaf(g[k], W1[k * DD + t], a);
    float h = fmaxf(a, 0.f);
    float p = h * W2[t];
    p = wave_sum(p);
    int lane = t & 63, w = t >> 6;
    if (lane == 0) red[w] = p;
    __syncthreads();
    if (t == 0) out[gi] = red[0] + red[1] + b2[0];
}

extern "C" void kernel_launch(void* const* d_in, const int* in_sizes, int n_in,
                              void* d_out, int out_size, void* d_ws, size_t ws_size,
                              hipStream_t stream) {
    const float* x    = (const float*)d_in[0];
    const int*   ei   = (const int*)d_in[1];
    const int*   bat  = (const int*)d_in[3];
    const float* Wg1  = (const float*)d_in[4];
    const float* as1  = (const float*)d_in[5];
    const float* ad1  = (const float*)d_in[6];
    const float* bg1  = (const float*)d_in[7];
    const float* Wg2  = (const float*)d_in[8];
    const float* as2  = (const float*)d_in[9];
    const float* ad2  = (const float*)d_in[10];
    const float* bg2  = (const float*)d_in[11];
    const float* Wl1  = (const float*)d_in[12];
    const float* bl1  = (const float*)d_in[13];
    const float* Wl2  = (const float*)d_in[14];
    const float* bl2  = (const float*)d_in[15];
    const int* src = ei;
    const int* dst = ei + NE;

    char* ws = (char*)d_ws;
    __half* Hh   = (__half*)(ws);                       // 12,800,000
    float* Y     = (float*)(ws + 12800000);             // 25,600,000
    float* asrc  = (float*)(ws + 38400000);             // 200,000
    float* adst  = (float*)(ws + 38600000);             // 200,000
    int*   deg   = (int*)  (ws + 38800000);             // 200,000  (zero region start)
    int*   ocnt  = (int*)  (ws + 39000000);             // 256
    float* gsum  = (float*)(ws + 39000256);             // 32,768
    int*   gcnt  = (int*)  (ws + 39033024);             // 256     (zero region end)
    int*   adj   = (int*)  (ws + 39033280);             // 12,800,000
    int2*  opair = (int2*) (ws + 51833280);             // 524,288

    // zero: deg + ocnt + gsum + gcnt = 233,280 bytes
    hipMemsetAsync(deg, 0, 233280, stream);

    // layer 1 gemm fused with adjacency build (independent work)
    k_gemm1_build<<<GEMM_BLOCKS + BUILD_BLOCKS, 256, 0, stream>>>(
        x, Wg1, as1, ad1, Hh, asrc, adst, src, dst, deg, adj, opair, ocnt);
    k_aggr<<<(NN + 3) / 4, 256, 0, stream>>>(Hh, asrc, adst, deg, adj, opair, ocnt, bg1, Y);
    k_gemm<<<GEMM_BLOCKS, 256, 0, stream>>>(Y, Wg2, as2, ad2, Hh, asrc, adst);
    k_aggr<<<(NN + 3) / 4, 256, 0, stream>>>(Hh, asrc, adst, deg, adj, opair, ocnt, bg2, Y);

    k_pool<<<256, 256, 0, stream>>>(Y, bat, gsum, gcnt);
    k_mlp <<<NG, 128, 0, stream>>>(gsum, gcnt, Wl1, bl1, Wl2, bl2, (float*)d_out);
}

// Round 7
// 312.785 us; speedup vs baseline: 1.1650x; 1.0422x over previous
//
#include <hip/hip_runtime.h>
#include <hip/hip_fp16.h>
#include <math.h>

#define NN 50000
#define NE 800000
#define DD 128
#define NG 64
#define NEG 0.2f
#define KMAX 64                  // fixed-width adjacency slots per node
#define OCAP 65536               // overflow pair capacity (never hit: deg<=~40)
#define GEMM_BLOCKS ((NN + 31) / 32)          // 1563
#define BUILD_BLOCKS ((NE / 4 + 255) / 256)   // 782

__device__ __forceinline__ float leaky(float x) { return x >= 0.f ? x : NEG * x; }

__device__ __forceinline__ float wave_sum(float v) {
    #pragma unroll
    for (int o = 32; o; o >>= 1) v += __shfl_xor(v, o, 64);
    return v;
}

// ---------------- gemm body ----------------
// 4 waves/block, 32 rows/block (8/wave). X tile in LDS (16 KB), W streamed
// from global (L2-resident) with one-iteration (8-k) register prefetch.
__device__ __forceinline__ void gemm_body(
        int gblk, const float* __restrict__ X, const float* __restrict__ W,
        const float* __restrict__ att_s, const float* __restrict__ att_d,
        __half* __restrict__ Hh, float* __restrict__ asrc, float* __restrict__ adst) {
    __shared__ __align__(16) float Xs[32 * DD];    // 16 KB
    int tid = threadIdx.x;
    int rowbase = gblk * 32;
    {
        const float4* X4 = (const float4*)X;
        float4* Xs4 = (float4*)Xs;
        size_t base4 = (size_t)rowbase * (DD / 4);
        const size_t max4 = (size_t)NN * (DD / 4) - 1;
        #pragma unroll
        for (int i = 0; i < 4; i++) {              // 32*128/4/256
            size_t g = base4 + tid + i * 256;
            if (g > max4) g = max4;                // tail clamp (loads only)
            Xs4[tid + i * 256] = X4[g];
        }
    }
    __syncthreads();
    int lane = tid & 63;
    int w = tid >> 6;
    int wrow = w * 8;
    float2 acc[8];
    #pragma unroll
    for (int r = 0; r < 8; r++) acc[r] = make_float2(0.f, 0.f);

    const float2* W2 = (const float2*)W;           // W[k][2l..2l+1] = W2[k*64+l]
    float2 wa[4], wb[4];
    #pragma unroll
    for (int u = 0; u < 4; u++) wa[u] = W2[u * 64 + lane];
    #pragma unroll
    for (int u = 0; u < 4; u++) wb[u] = W2[(4 + u) * 64 + lane];

    #pragma unroll 1
    for (int k0 = 0; k0 < DD; k0 += 8) {
        float2 na[4], nb[4];
        int kp = (k0 + 8) & 127;                   // wrap: last iter loads k=0 (unused)
        #pragma unroll
        for (int u = 0; u < 4; u++) na[u] = W2[(kp + u) * 64 + lane];
        #pragma unroll
        for (int u = 0; u < 4; u++) nb[u] = W2[(kp + 4 + u) * 64 + lane];
        #pragma unroll
        for (int r = 0; r < 8; r++) {
            float4 xv = *(const float4*)&Xs[(wrow + r) * DD + k0];      // broadcast
            float4 xw = *(const float4*)&Xs[(wrow + r) * DD + k0 + 4];
            acc[r].x = fmaf(xv.x, wa[0].x, acc[r].x);
            acc[r].y = fmaf(xv.x, wa[0].y, acc[r].y);
            acc[r].x = fmaf(xv.y, wa[1].x, acc[r].x);
            acc[r].y = fmaf(xv.y, wa[1].y, acc[r].y);
            acc[r].x = fmaf(xv.z, wa[2].x, acc[r].x);
            acc[r].y = fmaf(xv.z, wa[2].y, acc[r].y);
            acc[r].x = fmaf(xv.w, wa[3].x, acc[r].x);
            acc[r].y = fmaf(xv.w, wa[3].y, acc[r].y);
            acc[r].x = fmaf(xw.x, wb[0].x, acc[r].x);
            acc[r].y = fmaf(xw.x, wb[0].y, acc[r].y);
            acc[r].x = fmaf(xw.y, wb[1].x, acc[r].x);
            acc[r].y = fmaf(xw.y, wb[1].y, acc[r].y);
            acc[r].x = fmaf(xw.z, wb[2].x, acc[r].x);
            acc[r].y = fmaf(xw.z, wb[2].y, acc[r].y);
            acc[r].x = fmaf(xw.w, wb[3].x, acc[r].x);
            acc[r].y = fmaf(xw.w, wb[3].y, acc[r].y);
        }
        #pragma unroll
        for (int u = 0; u < 4; u++) { wa[u] = na[u]; wb[u] = nb[u]; }
    }
    float2 as = ((const float2*)att_s)[lane];
    float2 ad = ((const float2*)att_d)[lane];
    #pragma unroll
    for (int r = 0; r < 8; r++) {
        int rr = rowbase + wrow + r;
        float ps = acc[r].x * as.x + acc[r].y * as.y;
        float pd = acc[r].x * ad.x + acc[r].y * ad.y;
        #pragma unroll
        for (int o = 32; o; o >>= 1) {
            ps += __shfl_xor(ps, o, 64);
            pd += __shfl_xor(pd, o, 64);
        }
        if (rr < NN) {
            ((__half2*)Hh)[(size_t)rr * 64 + lane] = __floats2half2_rn(acc[r].x, acc[r].y);
            if (lane == 0) { asrc[rr] = ps; adst[rr] = pd; }
        }
    }
}

// adjacency build: rank from atomicAdd; ushort slots (src < 65536) -> the
// per-store dirty sector is 2B-packed: ~halves HBM write amplification.
__device__ __forceinline__ void build_body(
        int bblk, const int* __restrict__ src, const int* __restrict__ dst,
        int* __restrict__ deg, unsigned short* __restrict__ adj,
        int2* __restrict__ opairs, int* __restrict__ ocnt) {
    int e = bblk * 256 + threadIdx.x;              // group of 4 edges
    if (e < NE / 4) {
        int4 s = ((const int4*)src)[e];
        int4 d = ((const int4*)dst)[e];
        int r0 = atomicAdd(&deg[d.x], 1);
        int r1 = atomicAdd(&deg[d.y], 1);
        int r2 = atomicAdd(&deg[d.z], 1);
        int r3 = atomicAdd(&deg[d.w], 1);
        if (r0 < KMAX) adj[(d.x << 6) + r0] = (unsigned short)s.x;
        else { int o = atomicAdd(ocnt, 1); if (o < OCAP) opairs[o] = make_int2(s.x, d.x); }
        if (r1 < KMAX) adj[(d.y << 6) + r1] = (unsigned short)s.y;
        else { int o = atomicAdd(ocnt, 1); if (o < OCAP) opairs[o] = make_int2(s.y, d.y); }
        if (r2 < KMAX) adj[(d.z << 6) + r2] = (unsigned short)s.z;
        else { int o = atomicAdd(ocnt, 1); if (o < OCAP) opairs[o] = make_int2(s.z, d.z); }
        if (r3 < KMAX) adj[(d.w << 6) + r3] = (unsigned short)s.w;
        else { int o = atomicAdd(ocnt, 1); if (o < OCAP) opairs[o] = make_int2(s.w, d.w); }
    }
}

// fused layer-1 gemm || adjacency build, role-interleaved 2:1 so build blocks
// are co-resident with gemm blocks from t=0 (build hides under gemm VALU).
__launch_bounds__(256)
__global__ void k_gemm1_build(const float* __restrict__ X, const float* __restrict__ W,
                              const float* __restrict__ att_s, const float* __restrict__ att_d,
                              __half* __restrict__ Hh, float* __restrict__ asrc,
                              float* __restrict__ adst,
                              const int* __restrict__ src, const int* __restrict__ dst,
                              int* __restrict__ deg, unsigned short* __restrict__ adj,
                              int2* __restrict__ opairs, int* __restrict__ ocnt) {
    int r = blockIdx.x % 3;
    if (r == 2)
        build_body(blockIdx.x / 3, src, dst, deg, adj, opairs, ocnt);
    else
        gemm_body((blockIdx.x / 3) * 2 + r, X, W, att_s, att_d, Hh, asrc, adst);
}

__launch_bounds__(256)
__global__ void k_gemm(const float* __restrict__ X, const float* __restrict__ W,
                       const float* __restrict__ att_s, const float* __restrict__ att_d,
                       __half* __restrict__ Hh, float* __restrict__ asrc,
                       float* __restrict__ adst) {
    gemm_body(blockIdx.x, X, W, att_s, att_d, Hh, asrc, adst);
}

// ---------------- per-dst softmax + weighted aggregation ----------------
// One wave per dst node (WPB waves/block). Adjacency (ushort) + self-loop
// cached in regs via one coalesced load; per-edge exp cached in regs; pass 2
// gets (src, coef) via __shfl only. Quarter-wave gather: 16 lanes/row (uint4 =
// 8 fp16), 4 rows/load instr, 16 edges (4 KB) in flight per iteration.
// POOL=true: skip the Y write; accumulate relu(row+bias) into per-block LDS,
// flush per-graph runs with global atomics (global_mean_pool fused).
template<int WPB, bool POOL>
__launch_bounds__(WPB * 64)
__global__ void k_aggr(const __half* __restrict__ Hh, const float* __restrict__ asrc,
                       const float* __restrict__ adst, const int* __restrict__ degp,
                       const unsigned short* __restrict__ adj,
                       const int2* __restrict__ opairs, const int* __restrict__ ocnt,
                       const float* __restrict__ bias, const int* __restrict__ batch,
                       float* __restrict__ gsum, int* __restrict__ gcnt,
                       float* __restrict__ Y) {
    int tid = threadIdx.x;
    int lane = tid & 63;
    int h = lane >> 4;                 // quarter id: edge slot within group of 4
    int fl = lane & 15;                // feature lane (8 fp16 each)
    int w = tid >> 6;
    int v = blockIdx.x * WPB + w;      // grid sized exactly: v < NN always
    float adv = adst[v];
    float e_self = __expf(leaky(asrc[v] + adv));
    int deg = degp[v];
    bool self_in_reg = (deg < KMAX);
    int lim = self_in_reg ? deg + 1 : KMAX;   // reg-cached slots (incl. self)

    // pass 1: cache adjacency + exp in registers; lane==deg holds the self loop
    int   sarr = v;
    float evl  = 0.f;
    if (lane < lim) {
        sarr = (lane < deg) ? (int)adj[(v << 6) + lane] : v;
        evl  = (lane < deg) ? __expf(leaky(asrc[sarr] + adv)) : e_self;
    }
    int oc = 0;
    float sloc = evl;
    if (deg > KMAX) {                              // overflow (never in practice)
        oc = ocnt[0];
        if (oc > OCAP) oc = OCAP;
        for (int j = lane; j < oc; j += 64) {
            int2 p = opairs[j];
            if (p.y == v) sloc += __expf(leaky(asrc[p.x] + adv));
        }
    }
    float ssum = wave_sum(sloc) + (self_in_reg ? 0.f : e_self);
    float inv = 1.f / (ssum + 1e-16f);

    const uint4* H4 = (const uint4*)Hh;            // row = 16 uint4 (256 B)
    float acc[8];
    #pragma unroll
    for (int t = 0; t < 8; t++) acc[t] = 0.f;

    for (int j = 0; j < lim; j += 16) {            // 16 edges per batch
        int su[4]; float cu[4];
        #pragma unroll
        for (int u = 0; u < 4; u++) {
            int idx = j + 4 * u + h;
            int im  = idx & 63;
            int   s = __shfl(sarr, im, 64);
            float p = __shfl(evl,  im, 64);
            bool ok = idx < lim;
            su[u] = ok ? s : v;
            cu[u] = ok ? p * inv : 0.f;
        }
        uint4 hv[4];
        #pragma unroll
        for (int u = 0; u < 4; u++)
            hv[u] = H4[(size_t)su[u] * 16 + fl];   // 4 independent 1KB wave-loads
        #pragma unroll
        for (int u = 0; u < 4; u++) {
            const __half2* p2 = (const __half2*)&hv[u];
            #pragma unroll
            for (int t = 0; t < 4; t++) {
                float2 f = __half22float2(p2[t]);
                acc[2 * t]     = fmaf(cu[u], f.x, acc[2 * t]);
                acc[2 * t + 1] = fmaf(cu[u], f.y, acc[2 * t + 1]);
            }
        }
    }
    if (!self_in_reg) {                            // deferred self + overflow
        {
            float c0 = (h == 0) ? e_self * inv : 0.f;
            uint4 hv = H4[(size_t)v * 16 + fl];
            const __half2* p2 = (const __half2*)&hv;
            #pragma unroll
            for (int t = 0; t < 4; t++) {
                float2 f = __half22float2(p2[t]);
                acc[2 * t]     = fmaf(c0, f.x, acc[2 * t]);
                acc[2 * t + 1] = fmaf(c0, f.y, acc[2 * t + 1]);
            }
        }
        for (int j = 0; j < oc; ++j) {             // expected 0 iterations
            int2 p = opairs[j];
            if (p.y != v) continue;
            float c = (h == 0) ? __expf(leaky(asrc[p.x] + adv)) * inv : 0.f;
            uint4 hv = H4[(size_t)p.x * 16 + fl];
            const __half2* p2 = (const __half2*)&hv;
            #pragma unroll
            for (int t = 0; t < 4; t++) {
                float2 f = __half22float2(p2[t]);
                acc[2 * t]     = fmaf(c, f.x, acc[2 * t]);
                acc[2 * t + 1] = fmaf(c, f.y, acc[2 * t + 1]);
            }
        }
    }
    // combine the 4 quarters
    #pragma unroll
    for (int t = 0; t < 8; t++) {
        acc[t] += __shfl_xor(acc[t], 16, 64);
        acc[t] += __shfl_xor(acc[t], 32, 64);
    }
    if constexpr (POOL) {
        __shared__ float sh[WPB][DD];              // per-node relu'd rows
        __shared__ int sb[WPB];
        if (lane < 16) {
            const float4* B4 = (const float4*)bias;
            float4 b0 = B4[2 * fl], b1 = B4[2 * fl + 1];
            float4 o0, o1;
            o0.x = fmaxf(acc[0] + b0.x, 0.f);
            o0.y = fmaxf(acc[1] + b0.y, 0.f);
            o0.z = fmaxf(acc[2] + b0.z, 0.f);
            o0.w = fmaxf(acc[3] + b0.w, 0.f);
            o1.x = fmaxf(acc[4] + b1.x, 0.f);
            o1.y = fmaxf(acc[5] + b1.y, 0.f);
            o1.z = fmaxf(acc[6] + b1.z, 0.f);
            o1.w = fmaxf(acc[7] + b1.w, 0.f);
            *(float4*)&sh[w][8 * fl]     = o0;
            *(float4*)&sh[w][8 * fl + 4] = o1;
        }
        if (lane == 0) sb[w] = batch[v];
        __syncthreads();
        if (tid < DD) {                            // per-feature run flush
            int f = tid;
            float a = 0.f; int run = 0; int bcur = sb[0];
            #pragma unroll
            for (int r = 0; r < WPB; r++) {
                int b = sb[r];
                if (b != bcur) {
                    atomicAdd(&gsum[bcur * DD + f], a);
                    if (f == 0) atomicAdd(&gcnt[bcur], run);
                    a = 0.f; run = 0; bcur = b;
                }
                a += sh[r][f]; run++;
            }
            atomicAdd(&gsum[bcur * DD + f], a);
            if (f == 0) atomicAdd(&gcnt[bcur], run);
        }
    } else {
        if (lane < 16) {
            const float4* B4 = (const float4*)bias;
            float4 b0 = B4[2 * fl], b1 = B4[2 * fl + 1];
            float4 o0, o1;
            o0.x = fmaxf(acc[0] + b0.x, 0.f);
            o0.y = fmaxf(acc[1] + b0.y, 0.f);
            o0.z = fmaxf(acc[2] + b0.z, 0.f);
            o0.w = fmaxf(acc[3] + b0.w, 0.f);
            o1.x = fmaxf(acc[4] + b1.x, 0.f);
            o1.y = fmaxf(acc[5] + b1.y, 0.f);
            o1.z = fmaxf(acc[6] + b1.z, 0.f);
            o1.w = fmaxf(acc[7] + b1.w, 0.f);
            float4* Yo = (float4*)(Y + (size_t)v * DD);
            Yo[2 * fl]     = o0;
            Yo[2 * fl + 1] = o1;
        }
    }
}

// ---------------- final MLP: relu(g@W1+b1)@W2+b2 ----------------
__launch_bounds__(128)
__global__ void k_mlp(const float* __restrict__ gsum, const int* __restrict__ gcnt,
                      const float* __restrict__ W1, const float* __restrict__ b1,
                      const float* __restrict__ W2, const float* __restrict__ b2,
                      float* __restrict__ out) {
    __shared__ float g[DD];
    __shared__ float red[2];
    int gi = blockIdx.x, t = threadIdx.x;
    float cnt = fmaxf((float)gcnt[gi], 1.f);
    g[t] = gsum[gi * DD + t] / cnt;
    __syncthreads();
    float a = b1[t];
    #pragma unroll 4
    for (int k = 0; k < DD; k++) a = fmaf(g[k], W1[k * DD + t], a);
    float h = fmaxf(a, 0.f);
    float p = h * W2[t];
    p = wave_sum(p);
    int lane = t & 63, w = t >> 6;
    if (lane == 0) red[w] = p;
    __syncthreads();
    if (t == 0) out[gi] = red[0] + red[1] + b2[0];
}

extern "C" void kernel_launch(void* const* d_in, const int* in_sizes, int n_in,
                              void* d_out, int out_size, void* d_ws, size_t ws_size,
                              hipStream_t stream) {
    const float* x    = (const float*)d_in[0];
    const int*   ei   = (const int*)d_in[1];
    const int*   bat  = (const int*)d_in[3];
    const float* Wg1  = (const float*)d_in[4];
    const float* as1  = (const float*)d_in[5];
    const float* ad1  = (const float*)d_in[6];
    const float* bg1  = (const float*)d_in[7];
    const float* Wg2  = (const float*)d_in[8];
    const float* as2  = (const float*)d_in[9];
    const float* ad2  = (const float*)d_in[10];
    const float* bg2  = (const float*)d_in[11];
    const float* Wl1  = (const float*)d_in[12];
    const float* bl1  = (const float*)d_in[13];
    const float* Wl2  = (const float*)d_in[14];
    const float* bl2  = (const float*)d_in[15];
    const int* src = ei;
    const int* dst = ei + NE;

    char* ws = (char*)d_ws;
    __half* Hh   = (__half*)(ws);                       // 12,800,000
    float* Y     = (float*)(ws + 12800000);             // 25,600,000
    float* asrc  = (float*)(ws + 38400000);             // 200,000
    float* adst  = (float*)(ws + 38600000);             // 200,000
    int*   deg   = (int*)  (ws + 38800000);             // 200,000  (zero region start)
    int*   ocnt  = (int*)  (ws + 39000000);             // 256
    float* gsum  = (float*)(ws + 39000256);             // 32,768
    int*   gcnt  = (int*)  (ws + 39033024);             // 256     (zero region end)
    unsigned short* adj = (unsigned short*)(ws + 39033280);  // 6,400,000
    int2*  opair = (int2*) (ws + 45433280);             // 524,288

    // zero: deg + ocnt + gsum + gcnt = 233,280 bytes
    hipMemsetAsync(deg, 0, 233280, stream);

    // layer 1 gemm (2 of 3 blocks) interleaved with adjacency build (1 of 3)
    k_gemm1_build<<<3 * BUILD_BLOCKS, 256, 0, stream>>>(
        x, Wg1, as1, ad1, Hh, asrc, adst, src, dst, deg, adj, opair, ocnt);
    k_aggr<4, false><<<NN / 4, 256, 0, stream>>>(
        Hh, asrc, adst, deg, adj, opair, ocnt, bg1, bat, nullptr, nullptr, Y);
    k_gemm<<<GEMM_BLOCKS, 256, 0, stream>>>(Y, Wg2, as2, ad2, Hh, asrc, adst);
    k_aggr<8, true><<<NN / 8, 512, 0, stream>>>(
        Hh, asrc, adst, deg, adj, opair, ocnt, bg2, bat, gsum, gcnt, nullptr);
    k_mlp<<<NG, 128, 0, stream>>>(gsum, gcnt, Wl1, bl1, Wl2, bl2, (float*)d_out);
}